// Round 4
// baseline (1090.370 us; speedup 1.0000x reference)
//
#include <hip/hip_runtime.h>

#define Nn 50000
#define Dd 64
#define Ee 800000
#define Ll 3
#define Rr 2
#define Gg 128
#define Cc 10
#define NT 3125            // 16-node tiles
#define NRT (Rr * NT)      // 6250 (relation, tile) buckets

typedef __attribute__((ext_vector_type(8))) short short8;
typedef __attribute__((ext_vector_type(4))) float f32x4;

__device__ __forceinline__ unsigned short bf16_rne(float x) {
  unsigned u = __float_as_uint(x);
  unsigned r = u + 0x7fffu + ((u >> 16) & 1u);
  return (unsigned short)(r >> 16);
}
__device__ __forceinline__ float bf16_tof(unsigned short b) {
  return __uint_as_float(((unsigned)b) << 16);
}

// ================= CSR build at (relation, 16-node-tile) granularity ========
__global__ __launch_bounds__(256) void k_hist(
    const int* __restrict__ dst, const int* __restrict__ et,
    int* __restrict__ counts)
{
  int e = blockIdx.x * 256 + threadIdx.x;
  if (e >= Ee) return;
  atomicAdd(&counts[et[e] * NT + (dst[e] >> 4)], 1);
}

// single-block exclusive scan over 6250 bucket counts
__global__ __launch_bounds__(1024) void k_scanT(
    const int* __restrict__ counts, int* __restrict__ offs,
    int* __restrict__ cursor)
{
  __shared__ int ts[1024];
  int t = threadIdx.x;
  int base = t * 7;
  int c[7];
  int s = 0;
#pragma unroll
  for (int i = 0; i < 7; ++i) {
    int idx = base + i;
    int v = (idx < NRT) ? counts[idx] : 0;
    c[i] = s;            // exclusive within chunk
    s += v;
  }
  ts[t] = s;
  __syncthreads();
  for (int d = 1; d < 1024; d <<= 1) {
    int v2 = (t >= d) ? ts[t - d] : 0;
    __syncthreads();
    ts[t] += v2;
    __syncthreads();
  }
  int tbase = (t > 0) ? ts[t - 1] : 0;
#pragma unroll
  for (int i = 0; i < 7; ++i) {
    int idx = base + i;
    if (idx < NRT) {
      int off = tbase + c[i];
      offs[idx] = off;
      cursor[idx] = off;
    }
  }
  if (t == 1023) offs[NRT] = ts[1023];
}

// epack = src | (local_dst << 16); order within bucket irrelevant
__global__ __launch_bounds__(256) void k_fill(
    const int* __restrict__ src, const int* __restrict__ dst,
    const int* __restrict__ et, int* __restrict__ cursor,
    unsigned* __restrict__ epack)
{
  int e = blockIdx.x * 256 + threadIdx.x;
  if (e >= Ee) return;
  int d = dst[e];
  int pos = atomicAdd(&cursor[et[e] * NT + (d >> 4)], 1);
  epack[pos] = (unsigned)src[e] | ((unsigned)(d & 15) << 16);
}

// ---------------- weight prep: W -> W^T split-bf16 (hi/lo) ------------------
__global__ __launch_bounds__(256) void k_prep(
    const float* __restrict__ selfW, const float* __restrict__ W1,
    const float* __restrict__ W2, unsigned short* __restrict__ wtHi,
    unsigned short* __restrict__ wtLo)
{
  int i = blockIdx.x * 256 + threadIdx.x;
  if (i >= Ll * 5 * 4096) return;
  int l = i / (5 * 4096);
  int rem = i - l * 5 * 4096;
  int m = rem >> 12;
  int e = rem & 4095;
  int k = e >> 6, c = e & 63;
  const float* p;
  if (m == 0)      p = selfW + (size_t)l * 4096;
  else if (m == 1) p = W1 + ((size_t)l * 2 + 0) * 4096;
  else if (m == 2) p = W2 + ((size_t)l * 2 + 0) * 4096;
  else if (m == 3) p = W1 + ((size_t)l * 2 + 1) * 4096;
  else             p = W2 + ((size_t)l * 2 + 1) * 4096;
  float w = p[e];
  unsigned short hi = bf16_rne(w);
  unsigned short lo = bf16_rne(w - bf16_tof(hi));
  size_t o = ((size_t)(l * 5 + m) * 64 + c) * 64 + k;
  wtHi[o] = hi;
  wtLo[o] = lo;
}

// ====== fused per-layer update: edge-parallel LDS gather + split-bf16 MFMA ==
#define WOFF(m, c, ks) ((size_t)(m)*4096 + (size_t)(c)*64 + (ks)*32 + koff)

#define GATHER1(J)                                                   \
  {                                                                  \
    unsigned p0 = epack[(J)];                                        \
    const float4 v0 = *(const float4*)&h[(size_t)(p0 & 0xFFFFu) * 64 + fq]; \
    int d0 = (int)((p0 >> 16) & 15u);                                \
    atomicAdd(&za[d0][fq + 0], v0.x);                                \
    atomicAdd(&za[d0][fq + 1], v0.y);                                \
    atomicAdd(&za[d0][fq + 2], v0.z);                                \
    atomicAdd(&za[d0][fq + 3], v0.w);                                \
  }

__global__ __launch_bounds__(64) void k_update(
    const float* __restrict__ h, const int* __restrict__ toffs,
    const unsigned* __restrict__ epack,
    const unsigned short* __restrict__ wtHi, const unsigned short* __restrict__ wtLo,
    const float* __restrict__ selfb, const float* __restrict__ eps,
    const float* __restrict__ b1, const float* __restrict__ b2,
    float* __restrict__ hn, int l)
{
  __shared__ __align__(16) unsigned short tbh[16 * 72];
  __shared__ __align__(16) unsigned short tbl[16 * 72];
  __shared__ float za[16][68];
  const int lane = threadIdx.x;
  const int task = blockIdx.x;
  const int idx15 = lane & 15;
  const int kg = lane >> 4;
  const int koff = kg * 8;
  const int eg = kg;                 // edge slot 0..3
  const int fq = idx15 << 2;         // feature quad base
  const int nodeA = task * 16 + idx15;

  // h row fragment (row = idx15, features koff..koff+7 per kstep)
  float f[2][8];
  {
    const float* hp = &h[(size_t)nodeA * 64 + koff];
    const float4 a0 = *(const float4*)(hp);
    const float4 a1 = *(const float4*)(hp + 4);
    const float4 b0 = *(const float4*)(hp + 32);
    const float4 b1v = *(const float4*)(hp + 36);
    f[0][0] = a0.x; f[0][1] = a0.y; f[0][2] = a0.z; f[0][3] = a0.w;
    f[0][4] = a1.x; f[0][5] = a1.y; f[0][6] = a1.z; f[0][7] = a1.w;
    f[1][0] = b0.x; f[1][1] = b0.y; f[1][2] = b0.z; f[1][3] = b0.w;
    f[1][4] = b1v.x; f[1][5] = b1v.y; f[1][6] = b1v.z; f[1][7] = b1v.w;
  }
  short8 ahi[2], alo[2];
#pragma unroll
  for (int ks = 0; ks < 2; ++ks)
#pragma unroll
    for (int j = 0; j < 8; ++j) {
      unsigned short hb = bf16_rne(f[ks][j]);
      ahi[ks][j] = (short)hb;
      alo[ks][j] = (short)bf16_rne(f[ks][j] - bf16_tof(hb));
    }

  const unsigned short* whi = wtHi + (size_t)l * 5 * 4096;
  const unsigned short* wlo = wtLo + (size_t)l * 5 * 4096;

  f32x4 facc[4];
#pragma unroll
  for (int cb = 0; cb < 4; ++cb) {
    int c = cb * 16 + idx15;
    float bi = selfb[l * 64 + c] + b2[((size_t)l * 2 + 0) * 64 + c] +
               b2[((size_t)l * 2 + 1) * 64 + c];
    facc[cb] = (f32x4){bi, bi, bi, bi};
  }
  // self GEMM (m = 0)
#pragma unroll
  for (int cb = 0; cb < 4; ++cb) {
    int c = cb * 16 + idx15;
#pragma unroll
    for (int ks = 0; ks < 2; ++ks) {
      const short8 bh = *(const short8*)&whi[WOFF(0, c, ks)];
      const short8 bl = *(const short8*)&wlo[WOFF(0, c, ks)];
      facc[cb] = __builtin_amdgcn_mfma_f32_16x16x32_bf16(ahi[ks], bh, facc[cb], 0, 0, 0);
      facc[cb] = __builtin_amdgcn_mfma_f32_16x16x32_bf16(ahi[ks], bl, facc[cb], 0, 0, 0);
      facc[cb] = __builtin_amdgcn_mfma_f32_16x16x32_bf16(alo[ks], bh, facc[cb], 0, 0, 0);
    }
  }

#pragma unroll
  for (int r = 0; r < Rr; ++r) {
    const int m1 = 1 + 2 * r, m2 = 2 + 2 * r;
    float er = 1.0f + eps[l * Rr + r];

    // -------- edge-parallel gather into za (4 edges/iter, 4-deep pipeline) --
#pragma unroll
    for (int i = lane; i < 16 * 68; i += 64) (&za[0][0])[i] = 0.0f;
    {
      int tb = toffs[r * NT + task];
      int te = toffs[r * NT + task + 1];
      int j = tb + eg;
      for (; j + 12 < te; j += 16) {
        unsigned p0 = epack[j];
        unsigned p1 = epack[j + 4];
        unsigned p2 = epack[j + 8];
        unsigned p3 = epack[j + 12];
        const float4 v0 = *(const float4*)&h[(size_t)(p0 & 0xFFFFu) * 64 + fq];
        const float4 v1 = *(const float4*)&h[(size_t)(p1 & 0xFFFFu) * 64 + fq];
        const float4 v2 = *(const float4*)&h[(size_t)(p2 & 0xFFFFu) * 64 + fq];
        const float4 v3 = *(const float4*)&h[(size_t)(p3 & 0xFFFFu) * 64 + fq];
        int d0 = (int)((p0 >> 16) & 15u), d1 = (int)((p1 >> 16) & 15u);
        int d2 = (int)((p2 >> 16) & 15u), d3 = (int)((p3 >> 16) & 15u);
        atomicAdd(&za[d0][fq + 0], v0.x); atomicAdd(&za[d0][fq + 1], v0.y);
        atomicAdd(&za[d0][fq + 2], v0.z); atomicAdd(&za[d0][fq + 3], v0.w);
        atomicAdd(&za[d1][fq + 0], v1.x); atomicAdd(&za[d1][fq + 1], v1.y);
        atomicAdd(&za[d1][fq + 2], v1.z); atomicAdd(&za[d1][fq + 3], v1.w);
        atomicAdd(&za[d2][fq + 0], v2.x); atomicAdd(&za[d2][fq + 1], v2.y);
        atomicAdd(&za[d2][fq + 2], v2.z); atomicAdd(&za[d2][fq + 3], v2.w);
        atomicAdd(&za[d3][fq + 0], v3.x); atomicAdd(&za[d3][fq + 1], v3.y);
        atomicAdd(&za[d3][fq + 2], v3.z); atomicAdd(&za[d3][fq + 3], v3.w);
      }
      for (; j < te; j += 4) GATHER1(j);
    }
    asm volatile("s_waitcnt lgkmcnt(0)" ::: "memory");
    __builtin_amdgcn_sched_barrier(0);

    // z = er*h + za -> split bf16
    short8 zhi[2], zlo[2];
#pragma unroll
    for (int ks = 0; ks < 2; ++ks) {
      const float4 za0 = *(const float4*)&za[idx15][ks * 32 + koff];
      const float4 za1 = *(const float4*)&za[idx15][ks * 32 + koff + 4];
      float zf[8];
      zf[0] = er * f[ks][0] + za0.x; zf[1] = er * f[ks][1] + za0.y;
      zf[2] = er * f[ks][2] + za0.z; zf[3] = er * f[ks][3] + za0.w;
      zf[4] = er * f[ks][4] + za1.x; zf[5] = er * f[ks][5] + za1.y;
      zf[6] = er * f[ks][6] + za1.z; zf[7] = er * f[ks][7] + za1.w;
#pragma unroll
      for (int j = 0; j < 8; ++j) {
        unsigned short hb = bf16_rne(zf[j]);
        zhi[ks][j] = (short)hb;
        zlo[ks][j] = (short)bf16_rne(zf[j] - bf16_tof(hb));
      }
    }

    f32x4 tacc[4];
#pragma unroll
    for (int cb = 0; cb < 4; ++cb) {
      float bi = b1[((size_t)l * 2 + r) * 64 + cb * 16 + idx15];
      tacc[cb] = (f32x4){bi, bi, bi, bi};
    }
#pragma unroll
    for (int cb = 0; cb < 4; ++cb) {
      int c = cb * 16 + idx15;
#pragma unroll
      for (int ks = 0; ks < 2; ++ks) {
        const short8 bh = *(const short8*)&whi[WOFF(m1, c, ks)];
        const short8 bl = *(const short8*)&wlo[WOFF(m1, c, ks)];
        tacc[cb] = __builtin_amdgcn_mfma_f32_16x16x32_bf16(zhi[ks], bh, tacc[cb], 0, 0, 0);
        tacc[cb] = __builtin_amdgcn_mfma_f32_16x16x32_bf16(zhi[ks], bl, tacc[cb], 0, 0, 0);
        tacc[cb] = __builtin_amdgcn_mfma_f32_16x16x32_bf16(zlo[ks], bh, tacc[cb], 0, 0, 0);
      }
    }
    // relu -> split-bf16 -> LDS transpose bounce (single wave, no barrier)
#pragma unroll
    for (int cb = 0; cb < 4; ++cb)
#pragma unroll
      for (int q = 0; q < 4; ++q) {
        float tv = fmaxf(tacc[cb][q], 0.0f);
        unsigned short hb = bf16_rne(tv);
        tbh[(kg * 4 + q) * 72 + cb * 16 + idx15] = hb;
        tbl[(kg * 4 + q) * 72 + cb * 16 + idx15] = bf16_rne(tv - bf16_tof(hb));
      }
    asm volatile("s_waitcnt lgkmcnt(0)" ::: "memory");
    __builtin_amdgcn_sched_barrier(0);
    short8 thi[2], tlo[2];
#pragma unroll
    for (int ks = 0; ks < 2; ++ks) {
      thi[ks] = *(const short8*)&tbh[idx15 * 72 + ks * 32 + koff];
      tlo[ks] = *(const short8*)&tbl[idx15 * 72 + ks * 32 + koff];
    }
#pragma unroll
    for (int cb = 0; cb < 4; ++cb) {
      int c = cb * 16 + idx15;
#pragma unroll
      for (int ks = 0; ks < 2; ++ks) {
        const short8 bh = *(const short8*)&whi[WOFF(m2, c, ks)];
        const short8 bl = *(const short8*)&wlo[WOFF(m2, c, ks)];
        facc[cb] = __builtin_amdgcn_mfma_f32_16x16x32_bf16(thi[ks], bh, facc[cb], 0, 0, 0);
        facc[cb] = __builtin_amdgcn_mfma_f32_16x16x32_bf16(thi[ks], bl, facc[cb], 0, 0, 0);
        facc[cb] = __builtin_amdgcn_mfma_f32_16x16x32_bf16(tlo[ks], bh, facc[cb], 0, 0, 0);
      }
    }
  }
#pragma unroll
  for (int cb = 0; cb < 4; ++cb)
#pragma unroll
    for (int q = 0; q < 4; ++q)
      hn[((size_t)task * 16 + kg * 4 + q) * 64 + cb * 16 + idx15] = facc[cb][q];
}

// ---------------- global mean pool: segmented reduction (batch is sorted) ---
__global__ __launch_bounds__(256) void k_pool(
    const float* __restrict__ h, const int* __restrict__ batch,
    float* __restrict__ sums, float* __restrict__ cnts)
{
  int w = blockIdx.x * 4 + (threadIdx.x >> 6);
  int lane = threadIdx.x & 63;
  int start = w * 64;
  if (start >= Nn) return;
  int cnt = min(64, Nn - start);
  int bg = batch[min(start + lane, Nn - 1)];
  int cur = __shfl(bg, 0, 64);
  float acc = 0.0f;
  int run = 0;
  for (int i = 0; i < cnt; ++i) {
    int g = __shfl(bg, i, 64);
    float v = h[(size_t)(start + i) * 64 + lane];
    if (g != cur) {
      atomicAdd(&sums[(size_t)cur * 64 + lane], acc);
      if (lane == 0) atomicAdd(&cnts[cur], (float)run);
      acc = 0.0f; run = 0; cur = g;
    }
    acc += v; run++;
  }
  atomicAdd(&sums[(size_t)cur * 64 + lane], acc);
  if (lane == 0) atomicAdd(&cnts[cur], (float)run);
}

// ---------------- head: pooled -> relu(lin1) -> lin2 ------------------------
__global__ __launch_bounds__(256) void k_head(
    const float* __restrict__ sums, const float* __restrict__ cnts,
    const float* __restrict__ l1W, const float* __restrict__ l1b,
    const float* __restrict__ l2W, const float* __restrict__ l2b,
    float* __restrict__ out)
{
  int wave = threadIdx.x >> 6;
  int lane = threadIdx.x & 63;
  for (int g = wave; g < Gg; g += 4) {
    float p = sums[(size_t)g * Dd + lane] / fmaxf(cnts[g], 1.0f);
    float t = l1b[lane];
#pragma unroll
    for (int k = 0; k < Dd; ++k)
      t += __shfl(p, k, 64) * l1W[k * Dd + lane];
    t = fmaxf(t, 0.0f);
    float o = (lane < Cc) ? l2b[lane] : 0.0f;
#pragma unroll
    for (int k = 0; k < Dd; ++k) {
      float w = (lane < Cc) ? l2W[k * Cc + lane] : 0.0f;
      o += __shfl(t, k, 64) * w;
    }
    if (lane < Cc) out[(size_t)g * Cc + lane] = o;
  }
}

extern "C" void kernel_launch(void* const* d_in, const int* in_sizes, int n_in,
                              void* d_out, int out_size, void* d_ws, size_t ws_size,
                              hipStream_t stream)
{
  const float* x     = (const float*)d_in[0];
  const int*   ei    = (const int*)d_in[1];
  const int*   et    = (const int*)d_in[2];
  const int*   batch = (const int*)d_in[3];
  const float* selfW = (const float*)d_in[4];
  const float* selfb = (const float*)d_in[5];
  const float* eps   = (const float*)d_in[6];
  const float* W1    = (const float*)d_in[7];
  const float* b1    = (const float*)d_in[8];
  const float* W2    = (const float*)d_in[9];
  const float* b2    = (const float*)d_in[10];
  const float* l1W   = (const float*)d_in[11];
  const float* l1b   = (const float*)d_in[12];
  const float* l2W   = (const float*)d_in[13];
  const float* l2b   = (const float*)d_in[14];
  float* out = (float*)d_out;

  // ws layout:
  // buf0[N*D]f buf1[N*D]f sums[G*D]f cnts[G]f wtHi/wtLo[15*4096]u16
  // counts[NRT]i offs[NRT+1]i cursor[NRT]i epack[E]u32
  float* buf0 = (float*)d_ws;
  float* buf1 = buf0 + (size_t)Nn * Dd;
  float* sums = buf1 + (size_t)Nn * Dd;
  float* cnts = sums + (size_t)Gg * Dd;
  unsigned short* wtHi = (unsigned short*)(cnts + Gg);
  unsigned short* wtLo = wtHi + (size_t)Ll * 5 * 4096;
  int* counts = (int*)(wtLo + (size_t)Ll * 5 * 4096);
  int* offs   = counts + NRT;
  int* cursor = offs + NRT + 1;
  unsigned* epack = (unsigned*)(cursor + NRT);

  const int* src = ei;
  const int* dst = ei + Ee;

  hipMemsetAsync(sums, 0, (size_t)(Gg * Dd + Gg) * sizeof(float), stream);
  hipMemsetAsync(counts, 0, (size_t)NRT * sizeof(int), stream);
  k_prep<<<(Ll * 5 * 4096 + 255) / 256, 256, 0, stream>>>(selfW, W1, W2, wtHi, wtLo);

  // CSR build at tile granularity (graph static across layers)
  k_hist<<<(Ee + 255) / 256, 256, 0, stream>>>(dst, et, counts);
  k_scanT<<<1, 1024, 0, stream>>>(counts, offs, cursor);
  k_fill<<<(Ee + 255) / 256, 256, 0, stream>>>(src, dst, et, cursor, epack);

  const float* h = x;
  float* hn = buf0;
  for (int l = 0; l < Ll; ++l) {
    k_update<<<NT, 64, 0, stream>>>(h, offs, epack, wtHi, wtLo,
                                    selfb, eps, b1, b2, hn, l);
    h = hn;
    hn = (hn == buf0) ? buf1 : buf0;
  }
  k_pool<<<(Nn / 64 + 4) / 4, 256, 0, stream>>>(h, batch, sums, cnts);
  k_head<<<1, 256, 0, stream>>>(sums, cnts, l1W, l1b, l2W, l2b, out);
}

// Round 5
// 364.505 us; speedup vs baseline: 2.9914x; 2.9914x over previous
//
#include <hip/hip_runtime.h>

#define Nn 50000
#define Dd 64
#define Ee 800000
#define Ll 3
#define Rr 2
#define Gg 128
#define Cc 10
#define NR (Nn * Rr)
#define NB ((NR + 1023) / 1024)

typedef __attribute__((ext_vector_type(8))) short short8;
typedef __attribute__((ext_vector_type(4))) float f32x4;

__device__ __forceinline__ unsigned short bf16_rne(float x) {
  unsigned u = __float_as_uint(x);
  unsigned r = u + 0x7fffu + ((u >> 16) & 1u);
  return (unsigned short)(r >> 16);
}
__device__ __forceinline__ float bf16_tof(unsigned short b) {
  return __uint_as_float(((unsigned)b) << 16);
}

// ================= CSR build (per (relation,node); static across layers) ====
__global__ __launch_bounds__(256) void k_hist(
    const int* __restrict__ dst, const int* __restrict__ et,
    int* __restrict__ counts)
{
  int e = blockIdx.x * 256 + threadIdx.x;
  if (e >= Ee) return;
  atomicAdd(&counts[et[e] * Nn + dst[e]], 1);
}

__global__ __launch_bounds__(1024) void k_scan1(
    const int* __restrict__ counts, int* __restrict__ offs,
    int* __restrict__ btot)
{
  __shared__ int s[1024];
  int i = blockIdx.x * 1024 + threadIdx.x;
  int v = (i < NR) ? counts[i] : 0;
  s[threadIdx.x] = v;
  __syncthreads();
#pragma unroll
  for (int d = 1; d < 1024; d <<= 1) {
    int t = (threadIdx.x >= d) ? s[threadIdx.x - d] : 0;
    __syncthreads();
    s[threadIdx.x] += t;
    __syncthreads();
  }
  if (i < NR) offs[i + 1] = s[threadIdx.x];
  if (threadIdx.x == 1023) btot[blockIdx.x] = s[1023];
}

__global__ __launch_bounds__(128) void k_scan2(
    const int* __restrict__ btot, int* __restrict__ bscan)
{
  __shared__ int s[128];
  int v = (threadIdx.x < NB) ? btot[threadIdx.x] : 0;
  s[threadIdx.x] = v;
  __syncthreads();
#pragma unroll
  for (int d = 1; d < 128; d <<= 1) {
    int t = (threadIdx.x >= d) ? s[threadIdx.x - d] : 0;
    __syncthreads();
    s[threadIdx.x] += t;
    __syncthreads();
  }
  if (threadIdx.x < NB) bscan[threadIdx.x] = s[threadIdx.x] - v;  // exclusive
}

__global__ __launch_bounds__(1024) void k_scan3(
    const int* __restrict__ counts, const int* __restrict__ bscan,
    int* __restrict__ offs, int* __restrict__ cursor)
{
  int i = blockIdx.x * 1024 + threadIdx.x;
  if (i >= NR) return;
  int o = offs[i + 1] + bscan[blockIdx.x];
  offs[i + 1] = o;
  cursor[i] = o - counts[i];
  if (i == 0) offs[0] = 0;
}

__global__ __launch_bounds__(256) void k_fill(
    const int* __restrict__ src, const int* __restrict__ dst,
    const int* __restrict__ et, int* __restrict__ cursor,
    int* __restrict__ elist)
{
  int e = blockIdx.x * 256 + threadIdx.x;
  if (e >= Ee) return;
  int pos = atomicAdd(&cursor[et[e] * Nn + dst[e]], 1);
  elist[pos] = src[e];
}

// ---------------- weight prep: W -> W^T split-bf16 (hi/lo) ------------------
__global__ __launch_bounds__(256) void k_prep(
    const float* __restrict__ selfW, const float* __restrict__ W1,
    const float* __restrict__ W2, unsigned short* __restrict__ wtHi,
    unsigned short* __restrict__ wtLo)
{
  int i = blockIdx.x * 256 + threadIdx.x;
  if (i >= Ll * 5 * 4096) return;
  int l = i / (5 * 4096);
  int rem = i - l * 5 * 4096;
  int m = rem >> 12;
  int e = rem & 4095;
  int k = e >> 6, c = e & 63;
  const float* p;
  if (m == 0)      p = selfW + (size_t)l * 4096;
  else if (m == 1) p = W1 + ((size_t)l * 2 + 0) * 4096;
  else if (m == 2) p = W2 + ((size_t)l * 2 + 0) * 4096;
  else if (m == 3) p = W1 + ((size_t)l * 2 + 1) * 4096;
  else             p = W2 + ((size_t)l * 2 + 1) * 4096;
  float w = p[e];
  unsigned short hi = bf16_rne(w);
  unsigned short lo = bf16_rne(w - bf16_tof(hi));
  size_t o = ((size_t)(l * 5 + m) * 64 + c) * 64 + k;
  wtHi[o] = hi;
  wtLo[o] = lo;
}

// ====== fused per-layer update: pipelined CSR gather + split-bf16 MFMA ======
#define WOFF(m, c, ks) ((size_t)(m)*4096 + (size_t)(c)*64 + (ks)*32 + koff)

__global__ __launch_bounds__(256) void k_update(
    const float* __restrict__ h, const int* __restrict__ offs,
    const int* __restrict__ elist,
    const unsigned short* __restrict__ wtHi, const unsigned short* __restrict__ wtLo,
    const float* __restrict__ selfb, const float* __restrict__ eps,
    const float* __restrict__ b1, const float* __restrict__ b2,
    float* __restrict__ hn, int l)
{
  __shared__ __align__(16) unsigned short tbh[4][16 * 72];
  __shared__ __align__(16) unsigned short tbl[4][16 * 72];
  int wave = threadIdx.x >> 6;
  int lane = threadIdx.x & 63;
  int task = blockIdx.x * 4 + wave;
  if (task >= Nn / 16) return;          // 3125 tasks, no barriers anywhere
  int idx15 = lane & 15;
  int kg = lane >> 4;
  int koff = kg * 8;
  int nodeA = task * 16 + idx15;

  // h row fragment (row = idx15, features koff..koff+7 per kstep)
  float f[2][8];
  {
    const float* hp = &h[(size_t)nodeA * 64 + koff];
    const float4 a0 = *(const float4*)(hp);
    const float4 a1 = *(const float4*)(hp + 4);
    const float4 b0 = *(const float4*)(hp + 32);
    const float4 b1v = *(const float4*)(hp + 36);
    f[0][0] = a0.x; f[0][1] = a0.y; f[0][2] = a0.z; f[0][3] = a0.w;
    f[0][4] = a1.x; f[0][5] = a1.y; f[0][6] = a1.z; f[0][7] = a1.w;
    f[1][0] = b0.x; f[1][1] = b0.y; f[1][2] = b0.z; f[1][3] = b0.w;
    f[1][4] = b1v.x; f[1][5] = b1v.y; f[1][6] = b1v.z; f[1][7] = b1v.w;
  }
  short8 ahi[2], alo[2];
#pragma unroll
  for (int ks = 0; ks < 2; ++ks)
#pragma unroll
    for (int j = 0; j < 8; ++j) {
      unsigned short hb = bf16_rne(f[ks][j]);
      ahi[ks][j] = (short)hb;
      alo[ks][j] = (short)bf16_rne(f[ks][j] - bf16_tof(hb));
    }

  const unsigned short* whi = wtHi + (size_t)l * 5 * 4096;
  const unsigned short* wlo = wtLo + (size_t)l * 5 * 4096;

  f32x4 facc[4];
#pragma unroll
  for (int cb = 0; cb < 4; ++cb) {
    int c = cb * 16 + idx15;
    float bi = selfb[l * 64 + c] + b2[((size_t)l * 2 + 0) * 64 + c] +
               b2[((size_t)l * 2 + 1) * 64 + c];
    facc[cb] = (f32x4){bi, bi, bi, bi};
  }
  // self GEMM (m = 0)
#pragma unroll
  for (int cb = 0; cb < 4; ++cb) {
    int c = cb * 16 + idx15;
#pragma unroll
    for (int ks = 0; ks < 2; ++ks) {
      const short8 bh = *(const short8*)&whi[WOFF(0, c, ks)];
      const short8 bl = *(const short8*)&wlo[WOFF(0, c, ks)];
      facc[cb] = __builtin_amdgcn_mfma_f32_16x16x32_bf16(ahi[ks], bh, facc[cb], 0, 0, 0);
      facc[cb] = __builtin_amdgcn_mfma_f32_16x16x32_bf16(ahi[ks], bl, facc[cb], 0, 0, 0);
      facc[cb] = __builtin_amdgcn_mfma_f32_16x16x32_bf16(alo[ks], bh, facc[cb], 0, 0, 0);
    }
  }

#pragma unroll
  for (int r = 0; r < Rr; ++r) {
    const int m1 = 1 + 2 * r, m2 = 2 + 2 * r;
    float er = 1.0f + eps[l * Rr + r];

    // ---- CSR gather, 4-deep pipelined: 4 independent row fetches in flight
    float za[2][8];
#pragma unroll
    for (int ks = 0; ks < 2; ++ks)
#pragma unroll
      for (int j = 0; j < 8; ++j) za[ks][j] = 0.0f;
    {
      int aidx = r * Nn + nodeA;
      int jb = offs[aidx], je = offs[aidx + 1];
      int j = jb;
      for (; j + 3 < je; j += 4) {
        int s0 = elist[j], s1 = elist[j + 1], s2 = elist[j + 2], s3 = elist[j + 3];
        const float* p0 = &h[(size_t)s0 * 64 + koff];
        const float* p1 = &h[(size_t)s1 * 64 + koff];
        const float* p2 = &h[(size_t)s2 * 64 + koff];
        const float* p3 = &h[(size_t)s3 * 64 + koff];
        const float4 a0 = *(const float4*)(p0),     a1 = *(const float4*)(p1);
        const float4 a2 = *(const float4*)(p2),     a3 = *(const float4*)(p3);
        const float4 b0 = *(const float4*)(p0 + 4), b1q = *(const float4*)(p1 + 4);
        const float4 b2q = *(const float4*)(p2 + 4), b3 = *(const float4*)(p3 + 4);
        const float4 c0 = *(const float4*)(p0 + 32), c1 = *(const float4*)(p1 + 32);
        const float4 c2 = *(const float4*)(p2 + 32), c3 = *(const float4*)(p3 + 32);
        const float4 d0 = *(const float4*)(p0 + 36), d1 = *(const float4*)(p1 + 36);
        const float4 d2 = *(const float4*)(p2 + 36), d3 = *(const float4*)(p3 + 36);
        za[0][0] += (a0.x + a1.x) + (a2.x + a3.x);
        za[0][1] += (a0.y + a1.y) + (a2.y + a3.y);
        za[0][2] += (a0.z + a1.z) + (a2.z + a3.z);
        za[0][3] += (a0.w + a1.w) + (a2.w + a3.w);
        za[0][4] += (b0.x + b1q.x) + (b2q.x + b3.x);
        za[0][5] += (b0.y + b1q.y) + (b2q.y + b3.y);
        za[0][6] += (b0.z + b1q.z) + (b2q.z + b3.z);
        za[0][7] += (b0.w + b1q.w) + (b2q.w + b3.w);
        za[1][0] += (c0.x + c1.x) + (c2.x + c3.x);
        za[1][1] += (c0.y + c1.y) + (c2.y + c3.y);
        za[1][2] += (c0.z + c1.z) + (c2.z + c3.z);
        za[1][3] += (c0.w + c1.w) + (c2.w + c3.w);
        za[1][4] += (d0.x + d1.x) + (d2.x + d3.x);
        za[1][5] += (d0.y + d1.y) + (d2.y + d3.y);
        za[1][6] += (d0.z + d1.z) + (d2.z + d3.z);
        za[1][7] += (d0.w + d1.w) + (d2.w + d3.w);
      }
      for (; j < je; ++j) {
        int sn = elist[j];
        const float* hp = &h[(size_t)sn * 64 + koff];
        const float4 a0 = *(const float4*)(hp);
        const float4 a1 = *(const float4*)(hp + 4);
        const float4 b0 = *(const float4*)(hp + 32);
        const float4 b1v = *(const float4*)(hp + 36);
        za[0][0] += a0.x; za[0][1] += a0.y; za[0][2] += a0.z; za[0][3] += a0.w;
        za[0][4] += a1.x; za[0][5] += a1.y; za[0][6] += a1.z; za[0][7] += a1.w;
        za[1][0] += b0.x; za[1][1] += b0.y; za[1][2] += b0.z; za[1][3] += b0.w;
        za[1][4] += b1v.x; za[1][5] += b1v.y; za[1][6] += b1v.z; za[1][7] += b1v.w;
      }
    }

    short8 zhi[2], zlo[2];
#pragma unroll
    for (int ks = 0; ks < 2; ++ks)
#pragma unroll
      for (int j = 0; j < 8; ++j) {
        float zf = er * f[ks][j] + za[ks][j];
        unsigned short hb = bf16_rne(zf);
        zhi[ks][j] = (short)hb;
        zlo[ks][j] = (short)bf16_rne(zf - bf16_tof(hb));
      }

    f32x4 tacc[4];
#pragma unroll
    for (int cb = 0; cb < 4; ++cb) {
      float bi = b1[((size_t)l * 2 + r) * 64 + cb * 16 + idx15];
      tacc[cb] = (f32x4){bi, bi, bi, bi};
    }
#pragma unroll
    for (int cb = 0; cb < 4; ++cb) {
      int c = cb * 16 + idx15;
#pragma unroll
      for (int ks = 0; ks < 2; ++ks) {
        const short8 bh = *(const short8*)&whi[WOFF(m1, c, ks)];
        const short8 bl = *(const short8*)&wlo[WOFF(m1, c, ks)];
        tacc[cb] = __builtin_amdgcn_mfma_f32_16x16x32_bf16(zhi[ks], bh, tacc[cb], 0, 0, 0);
        tacc[cb] = __builtin_amdgcn_mfma_f32_16x16x32_bf16(zhi[ks], bl, tacc[cb], 0, 0, 0);
        tacc[cb] = __builtin_amdgcn_mfma_f32_16x16x32_bf16(zlo[ks], bh, tacc[cb], 0, 0, 0);
      }
    }
    // relu -> split-bf16 -> LDS transpose bounce (per-wave buffer, no barrier)
#pragma unroll
    for (int cb = 0; cb < 4; ++cb)
#pragma unroll
      for (int q = 0; q < 4; ++q) {
        float tv = fmaxf(tacc[cb][q], 0.0f);
        unsigned short hb = bf16_rne(tv);
        tbh[wave][(kg * 4 + q) * 72 + cb * 16 + idx15] = hb;
        tbl[wave][(kg * 4 + q) * 72 + cb * 16 + idx15] = bf16_rne(tv - bf16_tof(hb));
      }
    asm volatile("s_waitcnt lgkmcnt(0)" ::: "memory");
    __builtin_amdgcn_sched_barrier(0);
    short8 thi[2], tlo[2];
#pragma unroll
    for (int ks = 0; ks < 2; ++ks) {
      thi[ks] = *(const short8*)&tbh[wave][idx15 * 72 + ks * 32 + koff];
      tlo[ks] = *(const short8*)&tbl[wave][idx15 * 72 + ks * 32 + koff];
    }
#pragma unroll
    for (int cb = 0; cb < 4; ++cb) {
      int c = cb * 16 + idx15;
#pragma unroll
      for (int ks = 0; ks < 2; ++ks) {
        const short8 bh = *(const short8*)&whi[WOFF(m2, c, ks)];
        const short8 bl = *(const short8*)&wlo[WOFF(m2, c, ks)];
        facc[cb] = __builtin_amdgcn_mfma_f32_16x16x32_bf16(thi[ks], bh, facc[cb], 0, 0, 0);
        facc[cb] = __builtin_amdgcn_mfma_f32_16x16x32_bf16(thi[ks], bl, facc[cb], 0, 0, 0);
        facc[cb] = __builtin_amdgcn_mfma_f32_16x16x32_bf16(tlo[ks], bh, facc[cb], 0, 0, 0);
      }
    }
  }
#pragma unroll
  for (int cb = 0; cb < 4; ++cb)
#pragma unroll
    for (int q = 0; q < 4; ++q)
      hn[((size_t)task * 16 + kg * 4 + q) * 64 + cb * 16 + idx15] = facc[cb][q];
}

// ---------------- global mean pool: segmented reduction (batch is sorted) ---
__global__ __launch_bounds__(256) void k_pool(
    const float* __restrict__ h, const int* __restrict__ batch,
    float* __restrict__ sums, float* __restrict__ cnts)
{
  int w = blockIdx.x * 4 + (threadIdx.x >> 6);
  int lane = threadIdx.x & 63;
  int start = w * 64;
  if (start >= Nn) return;
  int cnt = min(64, Nn - start);
  int bg = batch[min(start + lane, Nn - 1)];
  int cur = __shfl(bg, 0, 64);
  float acc = 0.0f;
  int run = 0;
  for (int i = 0; i < cnt; ++i) {
    int g = __shfl(bg, i, 64);
    float v = h[(size_t)(start + i) * 64 + lane];
    if (g != cur) {
      atomicAdd(&sums[(size_t)cur * 64 + lane], acc);
      if (lane == 0) atomicAdd(&cnts[cur], (float)run);
      acc = 0.0f; run = 0; cur = g;
    }
    acc += v; run++;
  }
  atomicAdd(&sums[(size_t)cur * 64 + lane], acc);
  if (lane == 0) atomicAdd(&cnts[cur], (float)run);
}

// ---------------- head: pooled -> relu(lin1) -> lin2 (wave per graph) -------
__global__ __launch_bounds__(256) void k_head(
    const float* __restrict__ sums, const float* __restrict__ cnts,
    const float* __restrict__ l1W, const float* __restrict__ l1b,
    const float* __restrict__ l2W, const float* __restrict__ l2b,
    float* __restrict__ out)
{
  int wave = threadIdx.x >> 6;
  int lane = threadIdx.x & 63;
  int g = blockIdx.x * 4 + wave;
  if (g >= Gg) return;
  float p = sums[(size_t)g * Dd + lane] / fmaxf(cnts[g], 1.0f);
  float t = l1b[lane];
#pragma unroll
  for (int k = 0; k < Dd; ++k)
    t += __shfl(p, k, 64) * l1W[k * Dd + lane];
  t = fmaxf(t, 0.0f);
  float o = (lane < Cc) ? l2b[lane] : 0.0f;
#pragma unroll
  for (int k = 0; k < Dd; ++k) {
    float w = (lane < Cc) ? l2W[k * Cc + lane] : 0.0f;
    o += __shfl(t, k, 64) * w;
  }
  if (lane < Cc) out[(size_t)g * Cc + lane] = o;
}

extern "C" void kernel_launch(void* const* d_in, const int* in_sizes, int n_in,
                              void* d_out, int out_size, void* d_ws, size_t ws_size,
                              hipStream_t stream)
{
  const float* x     = (const float*)d_in[0];
  const int*   ei    = (const int*)d_in[1];
  const int*   et    = (const int*)d_in[2];
  const int*   batch = (const int*)d_in[3];
  const float* selfW = (const float*)d_in[4];
  const float* selfb = (const float*)d_in[5];
  const float* eps   = (const float*)d_in[6];
  const float* W1    = (const float*)d_in[7];
  const float* b1    = (const float*)d_in[8];
  const float* W2    = (const float*)d_in[9];
  const float* b2    = (const float*)d_in[10];
  const float* l1W   = (const float*)d_in[11];
  const float* l1b   = (const float*)d_in[12];
  const float* l2W   = (const float*)d_in[13];
  const float* l2b   = (const float*)d_in[14];
  float* out = (float*)d_out;

  // ws layout:
  // buf0[N*D]f buf1[N*D]f sums[G*D]f cnts[G]f wtHi/wtLo[15*4096]u16
  // counts[NR]i offs[NR+1]i cursor[NR]i btot[NB]i bscan[NB]i elist[E]i
  float* buf0 = (float*)d_ws;
  float* buf1 = buf0 + (size_t)Nn * Dd;
  float* sums = buf1 + (size_t)Nn * Dd;
  float* cnts = sums + (size_t)Gg * Dd;
  unsigned short* wtHi = (unsigned short*)(cnts + Gg);
  unsigned short* wtLo = wtHi + (size_t)Ll * 5 * 4096;
  int* counts = (int*)(wtLo + (size_t)Ll * 5 * 4096);
  int* offs   = counts + NR;
  int* cursor = offs + NR + 1;
  int* btot   = cursor + NR;
  int* bscan  = btot + NB;
  int* elist  = bscan + NB;

  const int* src = ei;
  const int* dst = ei + Ee;

  hipMemsetAsync(sums, 0, (size_t)(Gg * Dd + Gg) * sizeof(float), stream);
  hipMemsetAsync(counts, 0, (size_t)NR * sizeof(int), stream);
  k_prep<<<(Ll * 5 * 4096 + 255) / 256, 256, 0, stream>>>(selfW, W1, W2, wtHi, wtLo);

  // CSR build (graph static across layers)
  k_hist<<<(Ee + 255) / 256, 256, 0, stream>>>(dst, et, counts);
  k_scan1<<<NB, 1024, 0, stream>>>(counts, offs, btot);
  k_scan2<<<1, 128, 0, stream>>>(btot, bscan);
  k_scan3<<<NB, 1024, 0, stream>>>(counts, bscan, offs, cursor);
  k_fill<<<(Ee + 255) / 256, 256, 0, stream>>>(src, dst, et, cursor, elist);

  const float* h = x;
  float* hn = buf0;
  for (int l = 0; l < Ll; ++l) {
    k_update<<<(Nn / 16 + 3) / 4, 256, 0, stream>>>(h, offs, elist, wtHi, wtLo,
                                                    selfb, eps, b1, b2, hn, l);
    h = hn;
    hn = (hn == buf0) ? buf1 : buf0;
  }
  k_pool<<<(Nn / 64 + 4) / 4, 256, 0, stream>>>(h, batch, sums, cnts);
  k_head<<<32, 256, 0, stream>>>(sums, cnts, l1W, l1b, l2W, l2b, out);
}

// Round 6
// 338.068 us; speedup vs baseline: 3.2253x; 1.0782x over previous
//
#include <hip/hip_runtime.h>

#define Nn 50000
#define Dd 64
#define Ee 800000
#define Ll 3
#define Rr 2
#define Gg 128
#define Cc 10
#define NR (Nn * Rr)
#define NB ((NR + 1023) / 1024)
#define NT (Nn / 16)   // 3125 tasks

typedef __attribute__((ext_vector_type(8))) short short8;
typedef __attribute__((ext_vector_type(4))) float f32x4;

__device__ __forceinline__ unsigned short bf16_rne(float x) {
  unsigned u = __float_as_uint(x);
  unsigned r = u + 0x7fffu + ((u >> 16) & 1u);
  return (unsigned short)(r >> 16);
}
__device__ __forceinline__ float bf16_tof(unsigned short b) {
  return __uint_as_float(((unsigned)b) << 16);
}

// ================= CSR build (per (relation,node); static across layers) ====
__global__ __launch_bounds__(256) void k_hist(
    const int* __restrict__ dst, const int* __restrict__ et,
    int* __restrict__ counts)
{
  int e = blockIdx.x * 256 + threadIdx.x;
  if (e >= Ee) return;
  atomicAdd(&counts[et[e] * Nn + dst[e]], 1);
}

__global__ __launch_bounds__(1024) void k_scan1(
    const int* __restrict__ counts, int* __restrict__ offs,
    int* __restrict__ btot)
{
  __shared__ int s[1024];
  int i = blockIdx.x * 1024 + threadIdx.x;
  int v = (i < NR) ? counts[i] : 0;
  s[threadIdx.x] = v;
  __syncthreads();
#pragma unroll
  for (int d = 1; d < 1024; d <<= 1) {
    int t = (threadIdx.x >= d) ? s[threadIdx.x - d] : 0;
    __syncthreads();
    s[threadIdx.x] += t;
    __syncthreads();
  }
  if (i < NR) offs[i + 1] = s[threadIdx.x];
  if (threadIdx.x == 1023) btot[blockIdx.x] = s[1023];
}

__global__ __launch_bounds__(128) void k_scan2(
    const int* __restrict__ btot, int* __restrict__ bscan)
{
  __shared__ int s[128];
  int v = (threadIdx.x < NB) ? btot[threadIdx.x] : 0;
  s[threadIdx.x] = v;
  __syncthreads();
#pragma unroll
  for (int d = 1; d < 128; d <<= 1) {
    int t = (threadIdx.x >= d) ? s[threadIdx.x - d] : 0;
    __syncthreads();
    s[threadIdx.x] += t;
    __syncthreads();
  }
  if (threadIdx.x < NB) bscan[threadIdx.x] = s[threadIdx.x] - v;  // exclusive
}

__global__ __launch_bounds__(1024) void k_scan3(
    const int* __restrict__ counts, const int* __restrict__ bscan,
    int* __restrict__ offs, int* __restrict__ cursor)
{
  int i = blockIdx.x * 1024 + threadIdx.x;
  if (i >= NR) return;
  int o = offs[i + 1] + bscan[blockIdx.x];
  offs[i + 1] = o;
  cursor[i] = o - counts[i];
  if (i == 0) offs[0] = 0;
}

__global__ __launch_bounds__(256) void k_fill(
    const int* __restrict__ src, const int* __restrict__ dst,
    const int* __restrict__ et, int* __restrict__ cursor,
    int* __restrict__ elist)
{
  int e = blockIdx.x * 256 + threadIdx.x;
  if (e >= Ee) return;
  int pos = atomicAdd(&cursor[et[e] * Nn + dst[e]], 1);
  elist[pos] = src[e];
}

// ---------------- weight prep: W -> W^T split-bf16 (hi/lo) ------------------
__global__ __launch_bounds__(256) void k_prep(
    const float* __restrict__ selfW, const float* __restrict__ W1,
    const float* __restrict__ W2, unsigned short* __restrict__ wtHi,
    unsigned short* __restrict__ wtLo)
{
  int i = blockIdx.x * 256 + threadIdx.x;
  if (i >= Ll * 5 * 4096) return;
  int l = i / (5 * 4096);
  int rem = i - l * 5 * 4096;
  int m = rem >> 12;
  int e = rem & 4095;
  int k = e >> 6, c = e & 63;
  const float* p;
  if (m == 0)      p = selfW + (size_t)l * 4096;
  else if (m == 1) p = W1 + ((size_t)l * 2 + 0) * 4096;
  else if (m == 2) p = W2 + ((size_t)l * 2 + 0) * 4096;
  else if (m == 3) p = W1 + ((size_t)l * 2 + 1) * 4096;
  else             p = W2 + ((size_t)l * 2 + 1) * 4096;
  float w = p[e];
  unsigned short hi = bf16_rne(w);
  unsigned short lo = bf16_rne(w - bf16_tof(hi));
  size_t o = ((size_t)(l * 5 + m) * 64 + c) * 64 + k;
  wtHi[o] = hi;
  wtLo[o] = lo;
}

// ====== fused per-layer update: (task, relation) per wave + LDS combine =====
#define WOFF(m, c, ks) ((size_t)(m)*4096 + (size_t)(c)*64 + (ks)*32 + koff)

__global__ __launch_bounds__(128, 6) void k_update(
    const float* __restrict__ h, const int* __restrict__ offs,
    const int* __restrict__ elist,
    const unsigned short* __restrict__ wtHi, const unsigned short* __restrict__ wtLo,
    const float* __restrict__ selfb, const float* __restrict__ eps,
    const float* __restrict__ b1, const float* __restrict__ b2,
    float* __restrict__ hn, int l)
{
  __shared__ __align__(16) unsigned short tbh[2][16 * 72];
  __shared__ __align__(16) unsigned short tbl[2][16 * 72];
  __shared__ float xfer[16 * 65];       // padded: bank = row + col (mod 32)
  const int wave = threadIdx.x >> 6;    // = relation r
  const int lane = threadIdx.x & 63;
  const int task = blockIdx.x;
  const int r = wave;
  const int idx15 = lane & 15;
  const int kg = lane >> 4;
  const int koff = kg * 8;
  const int nodeA = task * 16 + idx15;

  // h row fragment (row = idx15, features koff..koff+7 per kstep)
  float f[2][8];
  {
    const float* hp = &h[(size_t)nodeA * 64 + koff];
    const float4 a0 = *(const float4*)(hp);
    const float4 a1 = *(const float4*)(hp + 4);
    const float4 b0 = *(const float4*)(hp + 32);
    const float4 b1v = *(const float4*)(hp + 36);
    f[0][0] = a0.x; f[0][1] = a0.y; f[0][2] = a0.z; f[0][3] = a0.w;
    f[0][4] = a1.x; f[0][5] = a1.y; f[0][6] = a1.z; f[0][7] = a1.w;
    f[1][0] = b0.x; f[1][1] = b0.y; f[1][2] = b0.z; f[1][3] = b0.w;
    f[1][4] = b1v.x; f[1][5] = b1v.y; f[1][6] = b1v.z; f[1][7] = b1v.w;
  }

  const unsigned short* whi = wtHi + (size_t)l * 5 * 4096;
  const unsigned short* wlo = wtLo + (size_t)l * 5 * 4096;
  const int m1 = 1 + 2 * r, m2 = 2 + 2 * r;
  const float er = 1.0f + eps[l * Rr + r];

  // ---- CSR gather for relation r, 4-deep pipelined --------------------------
  float za[2][8];
#pragma unroll
  for (int ks = 0; ks < 2; ++ks)
#pragma unroll
    for (int j = 0; j < 8; ++j) za[ks][j] = 0.0f;
  {
    int aidx = r * Nn + nodeA;
    int jb = offs[aidx], je = offs[aidx + 1];
    int j = jb;
    for (; j + 3 < je; j += 4) {
      int s0 = elist[j], s1 = elist[j + 1], s2 = elist[j + 2], s3 = elist[j + 3];
      const float* p0 = &h[(size_t)s0 * 64 + koff];
      const float* p1 = &h[(size_t)s1 * 64 + koff];
      const float* p2 = &h[(size_t)s2 * 64 + koff];
      const float* p3 = &h[(size_t)s3 * 64 + koff];
      const float4 a0 = *(const float4*)(p0),     a1 = *(const float4*)(p1);
      const float4 a2 = *(const float4*)(p2),     a3 = *(const float4*)(p3);
      const float4 b0 = *(const float4*)(p0 + 4), b1q = *(const float4*)(p1 + 4);
      const float4 b2q = *(const float4*)(p2 + 4), b3 = *(const float4*)(p3 + 4);
      const float4 c0 = *(const float4*)(p0 + 32), c1 = *(const float4*)(p1 + 32);
      const float4 c2 = *(const float4*)(p2 + 32), c3 = *(const float4*)(p3 + 32);
      const float4 d0 = *(const float4*)(p0 + 36), d1 = *(const float4*)(p1 + 36);
      const float4 d2 = *(const float4*)(p2 + 36), d3 = *(const float4*)(p3 + 36);
      za[0][0] += (a0.x + a1.x) + (a2.x + a3.x);
      za[0][1] += (a0.y + a1.y) + (a2.y + a3.y);
      za[0][2] += (a0.z + a1.z) + (a2.z + a3.z);
      za[0][3] += (a0.w + a1.w) + (a2.w + a3.w);
      za[0][4] += (b0.x + b1q.x) + (b2q.x + b3.x);
      za[0][5] += (b0.y + b1q.y) + (b2q.y + b3.y);
      za[0][6] += (b0.z + b1q.z) + (b2q.z + b3.z);
      za[0][7] += (b0.w + b1q.w) + (b2q.w + b3.w);
      za[1][0] += (c0.x + c1.x) + (c2.x + c3.x);
      za[1][1] += (c0.y + c1.y) + (c2.y + c3.y);
      za[1][2] += (c0.z + c1.z) + (c2.z + c3.z);
      za[1][3] += (c0.w + c1.w) + (c2.w + c3.w);
      za[1][4] += (d0.x + d1.x) + (d2.x + d3.x);
      za[1][5] += (d0.y + d1.y) + (d2.y + d3.y);
      za[1][6] += (d0.z + d1.z) + (d2.z + d3.z);
      za[1][7] += (d0.w + d1.w) + (d2.w + d3.w);
    }
    for (; j < je; ++j) {
      int sn = elist[j];
      const float* hp = &h[(size_t)sn * 64 + koff];
      const float4 a0 = *(const float4*)(hp);
      const float4 a1 = *(const float4*)(hp + 4);
      const float4 b0 = *(const float4*)(hp + 32);
      const float4 b1v = *(const float4*)(hp + 36);
      za[0][0] += a0.x; za[0][1] += a0.y; za[0][2] += a0.z; za[0][3] += a0.w;
      za[0][4] += a1.x; za[0][5] += a1.y; za[0][6] += a1.z; za[0][7] += a1.w;
      za[1][0] += b0.x; za[1][1] += b0.y; za[1][2] += b0.z; za[1][3] += b0.w;
      za[1][4] += b1v.x; za[1][5] += b1v.y; za[1][6] += b1v.z; za[1][7] += b1v.w;
    }
  }

  // z = er*h + za -> split bf16
  short8 zhi[2], zlo[2];
#pragma unroll
  for (int ks = 0; ks < 2; ++ks)
#pragma unroll
    for (int j = 0; j < 8; ++j) {
      float zf = er * f[ks][j] + za[ks][j];
      unsigned short hb = bf16_rne(zf);
      zhi[ks][j] = (short)hb;
      zlo[ks][j] = (short)bf16_rne(zf - bf16_tof(hb));
    }

  // MLP1: tacc = relu(z @ W1_r + b1_r)
  f32x4 tacc[4];
#pragma unroll
  for (int cb = 0; cb < 4; ++cb) {
    float bi = b1[((size_t)l * 2 + r) * 64 + cb * 16 + idx15];
    tacc[cb] = (f32x4){bi, bi, bi, bi};
  }
#pragma unroll
  for (int cb = 0; cb < 4; ++cb) {
    int c = cb * 16 + idx15;
#pragma unroll
    for (int ks = 0; ks < 2; ++ks) {
      const short8 bh = *(const short8*)&whi[WOFF(m1, c, ks)];
      const short8 bl = *(const short8*)&wlo[WOFF(m1, c, ks)];
      tacc[cb] = __builtin_amdgcn_mfma_f32_16x16x32_bf16(zhi[ks], bh, tacc[cb], 0, 0, 0);
      tacc[cb] = __builtin_amdgcn_mfma_f32_16x16x32_bf16(zhi[ks], bl, tacc[cb], 0, 0, 0);
      tacc[cb] = __builtin_amdgcn_mfma_f32_16x16x32_bf16(zlo[ks], bh, tacc[cb], 0, 0, 0);
    }
  }
  // relu -> split-bf16 -> LDS transpose bounce (per-wave buffer, no barrier)
#pragma unroll
  for (int cb = 0; cb < 4; ++cb)
#pragma unroll
    for (int q = 0; q < 4; ++q) {
      float tv = fmaxf(tacc[cb][q], 0.0f);
      unsigned short hb = bf16_rne(tv);
      tbh[wave][(kg * 4 + q) * 72 + cb * 16 + idx15] = hb;
      tbl[wave][(kg * 4 + q) * 72 + cb * 16 + idx15] = bf16_rne(tv - bf16_tof(hb));
    }
  asm volatile("s_waitcnt lgkmcnt(0)" ::: "memory");
  __builtin_amdgcn_sched_barrier(0);
  short8 thi[2], tlo[2];
#pragma unroll
  for (int ks = 0; ks < 2; ++ks) {
    thi[ks] = *(const short8*)&tbh[wave][idx15 * 72 + ks * 32 + koff];
    tlo[ks] = *(const short8*)&tbl[wave][idx15 * 72 + ks * 32 + koff];
  }

  // MLP2 (+ wave1: self GEMM); facc = partial output
  f32x4 facc[4];
#pragma unroll
  for (int cb = 0; cb < 4; ++cb) {
    int c = cb * 16 + idx15;
    float bi = b2[((size_t)l * 2 + r) * 64 + c];
    if (wave == 1) bi += selfb[l * 64 + c];
    facc[cb] = (f32x4){bi, bi, bi, bi};
  }
#pragma unroll
  for (int cb = 0; cb < 4; ++cb) {
    int c = cb * 16 + idx15;
#pragma unroll
    for (int ks = 0; ks < 2; ++ks) {
      const short8 bh = *(const short8*)&whi[WOFF(m2, c, ks)];
      const short8 bl = *(const short8*)&wlo[WOFF(m2, c, ks)];
      facc[cb] = __builtin_amdgcn_mfma_f32_16x16x32_bf16(thi[ks], bh, facc[cb], 0, 0, 0);
      facc[cb] = __builtin_amdgcn_mfma_f32_16x16x32_bf16(thi[ks], bl, facc[cb], 0, 0, 0);
      facc[cb] = __builtin_amdgcn_mfma_f32_16x16x32_bf16(tlo[ks], bh, facc[cb], 0, 0, 0);
    }
  }
  if (wave == 1) {
    short8 ahi[2], alo[2];
#pragma unroll
    for (int ks = 0; ks < 2; ++ks)
#pragma unroll
      for (int j = 0; j < 8; ++j) {
        unsigned short hb = bf16_rne(f[ks][j]);
        ahi[ks][j] = (short)hb;
        alo[ks][j] = (short)bf16_rne(f[ks][j] - bf16_tof(hb));
      }
#pragma unroll
    for (int cb = 0; cb < 4; ++cb) {
      int c = cb * 16 + idx15;
#pragma unroll
      for (int ks = 0; ks < 2; ++ks) {
        const short8 bh = *(const short8*)&whi[WOFF(0, c, ks)];
        const short8 bl = *(const short8*)&wlo[WOFF(0, c, ks)];
        facc[cb] = __builtin_amdgcn_mfma_f32_16x16x32_bf16(ahi[ks], bh, facc[cb], 0, 0, 0);
        facc[cb] = __builtin_amdgcn_mfma_f32_16x16x32_bf16(ahi[ks], bl, facc[cb], 0, 0, 0);
        facc[cb] = __builtin_amdgcn_mfma_f32_16x16x32_bf16(alo[ks], bh, facc[cb], 0, 0, 0);
      }
    }
    // deposit partial for wave0 to combine
#pragma unroll
    for (int cb = 0; cb < 4; ++cb)
#pragma unroll
      for (int q = 0; q < 4; ++q)
        xfer[(kg * 4 + q) * 65 + cb * 16 + idx15] = facc[cb][q];
  }
  __syncthreads();
  if (wave == 0) {
#pragma unroll
    for (int cb = 0; cb < 4; ++cb)
#pragma unroll
      for (int q = 0; q < 4; ++q) {
        int row = kg * 4 + q, col = cb * 16 + idx15;
        hn[((size_t)task * 16 + row) * 64 + col] =
            facc[cb][q] + xfer[row * 65 + col];
      }
  }
}

// ---------------- global mean pool: segmented reduction (batch is sorted) ---
__global__ __launch_bounds__(256) void k_pool(
    const float* __restrict__ h, const int* __restrict__ batch,
    float* __restrict__ sums, float* __restrict__ cnts)
{
  int w = blockIdx.x * 4 + (threadIdx.x >> 6);
  int lane = threadIdx.x & 63;
  int start = w * 64;
  if (start >= Nn) return;
  int cnt = min(64, Nn - start);
  int bg = batch[min(start + lane, Nn - 1)];
  int cur = __shfl(bg, 0, 64);
  float acc = 0.0f;
  int run = 0;
  for (int i = 0; i < cnt; ++i) {
    int g = __shfl(bg, i, 64);
    float v = h[(size_t)(start + i) * 64 + lane];
    if (g != cur) {
      atomicAdd(&sums[(size_t)cur * 64 + lane], acc);
      if (lane == 0) atomicAdd(&cnts[cur], (float)run);
      acc = 0.0f; run = 0; cur = g;
    }
    acc += v; run++;
  }
  atomicAdd(&sums[(size_t)cur * 64 + lane], acc);
  if (lane == 0) atomicAdd(&cnts[cur], (float)run);
}

// ---------------- head: pooled -> relu(lin1) -> lin2 (wave per graph) -------
__global__ __launch_bounds__(256) void k_head(
    const float* __restrict__ sums, const float* __restrict__ cnts,
    const float* __restrict__ l1W, const float* __restrict__ l1b,
    const float* __restrict__ l2W, const float* __restrict__ l2b,
    float* __restrict__ out)
{
  int wave = threadIdx.x >> 6;
  int lane = threadIdx.x & 63;
  int g = blockIdx.x * 4 + wave;
  if (g >= Gg) return;
  float p = sums[(size_t)g * Dd + lane] / fmaxf(cnts[g], 1.0f);
  float t = l1b[lane];
#pragma unroll
  for (int k = 0; k < Dd; ++k)
    t += __shfl(p, k, 64) * l1W[k * Dd + lane];
  t = fmaxf(t, 0.0f);
  float o = (lane < Cc) ? l2b[lane] : 0.0f;
#pragma unroll
  for (int k = 0; k < Dd; ++k) {
    float w = (lane < Cc) ? l2W[k * Cc + lane] : 0.0f;
    o += __shfl(t, k, 64) * w;
  }
  if (lane < Cc) out[(size_t)g * Cc + lane] = o;
}

extern "C" void kernel_launch(void* const* d_in, const int* in_sizes, int n_in,
                              void* d_out, int out_size, void* d_ws, size_t ws_size,
                              hipStream_t stream)
{
  const float* x     = (const float*)d_in[0];
  const int*   ei    = (const int*)d_in[1];
  const int*   et    = (const int*)d_in[2];
  const int*   batch = (const int*)d_in[3];
  const float* selfW = (const float*)d_in[4];
  const float* selfb = (const float*)d_in[5];
  const float* eps   = (const float*)d_in[6];
  const float* W1    = (const float*)d_in[7];
  const float* b1    = (const float*)d_in[8];
  const float* W2    = (const float*)d_in[9];
  const float* b2    = (const float*)d_in[10];
  const float* l1W   = (const float*)d_in[11];
  const float* l1b   = (const float*)d_in[12];
  const float* l2W   = (const float*)d_in[13];
  const float* l2b   = (const float*)d_in[14];
  float* out = (float*)d_out;

  // ws layout:
  // buf0[N*D]f buf1[N*D]f sums[G*D]f cnts[G]f wtHi/wtLo[15*4096]u16
  // counts[NR]i offs[NR+1]i cursor[NR]i btot[NB]i bscan[NB]i elist[E]i
  float* buf0 = (float*)d_ws;
  float* buf1 = buf0 + (size_t)Nn * Dd;
  float* sums = buf1 + (size_t)Nn * Dd;
  float* cnts = sums + (size_t)Gg * Dd;
  unsigned short* wtHi = (unsigned short*)(cnts + Gg);
  unsigned short* wtLo = wtHi + (size_t)Ll * 5 * 4096;
  int* counts = (int*)(wtLo + (size_t)Ll * 5 * 4096);
  int* offs   = counts + NR;
  int* cursor = offs + NR + 1;
  int* btot   = cursor + NR;
  int* bscan  = btot + NB;
  int* elist  = bscan + NB;

  const int* src = ei;
  const int* dst = ei + Ee;

  hipMemsetAsync(sums, 0, (size_t)(Gg * Dd + Gg) * sizeof(float), stream);
  hipMemsetAsync(counts, 0, (size_t)NR * sizeof(int), stream);
  k_prep<<<(Ll * 5 * 4096 + 255) / 256, 256, 0, stream>>>(selfW, W1, W2, wtHi, wtLo);

  // CSR build (graph static across layers)
  k_hist<<<(Ee + 255) / 256, 256, 0, stream>>>(dst, et, counts);
  k_scan1<<<NB, 1024, 0, stream>>>(counts, offs, btot);
  k_scan2<<<1, 128, 0, stream>>>(btot, bscan);
  k_scan3<<<NB, 1024, 0, stream>>>(counts, bscan, offs, cursor);
  k_fill<<<(Ee + 255) / 256, 256, 0, stream>>>(src, dst, et, cursor, elist);

  const float* h = x;
  float* hn = buf0;
  for (int l = 0; l < Ll; ++l) {
    k_update<<<NT, 128, 0, stream>>>(h, offs, elist, wtHi, wtLo,
                                     selfb, eps, b1, b2, hn, l);
    h = hn;
    hn = (hn == buf0) ? buf1 : buf0;
  }
  k_pool<<<(Nn / 64 + 4) / 4, 256, 0, stream>>>(h, batch, sums, cnts);
  k_head<<<32, 256, 0, stream>>>(sums, cnts, l1W, l1b, l2W, l2b, out);
}

// Round 7
// 296.752 us; speedup vs baseline: 3.6743x; 1.1392x over previous
//
#include <hip/hip_runtime.h>

#define Nn 50000
#define Dd 64
#define Ee 800000
#define Ll 3
#define Rr 2
#define Gg 128
#define Cc 10
#define NR (Nn * Rr)
#define NB ((NR + 1023) / 1024)
#define NT (Nn / 16)   // 3125 tasks

typedef __attribute__((ext_vector_type(8))) short short8;
typedef __attribute__((ext_vector_type(4))) float f32x4;

__device__ __forceinline__ unsigned short bf16_rne(float x) {
  unsigned u = __float_as_uint(x);
  unsigned r = u + 0x7fffu + ((u >> 16) & 1u);
  return (unsigned short)(r >> 16);
}
__device__ __forceinline__ float bf16_tof(unsigned short b) {
  return __uint_as_float(((unsigned)b) << 16);
}
// accumulate 8 bf16 (packed in uint4) into z[0..7], f32
__device__ __forceinline__ void acc8(float* z, uint4 u) {
  z[0] += __uint_as_float(u.x << 16);
  z[1] += __uint_as_float(u.x & 0xffff0000u);
  z[2] += __uint_as_float(u.y << 16);
  z[3] += __uint_as_float(u.y & 0xffff0000u);
  z[4] += __uint_as_float(u.z << 16);
  z[5] += __uint_as_float(u.z & 0xffff0000u);
  z[6] += __uint_as_float(u.w << 16);
  z[7] += __uint_as_float(u.w & 0xffff0000u);
}

// ================= CSR build (per (relation,node); static across layers) ====
__global__ __launch_bounds__(256) void k_hist(
    const int* __restrict__ dst, const int* __restrict__ et,
    int* __restrict__ counts)
{
  int e = blockIdx.x * 256 + threadIdx.x;
  if (e >= Ee) return;
  atomicAdd(&counts[et[e] * Nn + dst[e]], 1);
}

__global__ __launch_bounds__(1024) void k_scan1(
    const int* __restrict__ counts, int* __restrict__ offs,
    int* __restrict__ btot)
{
  __shared__ int s[1024];
  int i = blockIdx.x * 1024 + threadIdx.x;
  int v = (i < NR) ? counts[i] : 0;
  s[threadIdx.x] = v;
  __syncthreads();
#pragma unroll
  for (int d = 1; d < 1024; d <<= 1) {
    int t = (threadIdx.x >= d) ? s[threadIdx.x - d] : 0;
    __syncthreads();
    s[threadIdx.x] += t;
    __syncthreads();
  }
  if (i < NR) offs[i + 1] = s[threadIdx.x];
  if (threadIdx.x == 1023) btot[blockIdx.x] = s[1023];
}

__global__ __launch_bounds__(128) void k_scan2(
    const int* __restrict__ btot, int* __restrict__ bscan)
{
  __shared__ int s[128];
  int v = (threadIdx.x < NB) ? btot[threadIdx.x] : 0;
  s[threadIdx.x] = v;
  __syncthreads();
#pragma unroll
  for (int d = 1; d < 128; d <<= 1) {
    int t = (threadIdx.x >= d) ? s[threadIdx.x - d] : 0;
    __syncthreads();
    s[threadIdx.x] += t;
    __syncthreads();
  }
  if (threadIdx.x < NB) bscan[threadIdx.x] = s[threadIdx.x] - v;  // exclusive
}

__global__ __launch_bounds__(1024) void k_scan3(
    const int* __restrict__ counts, const int* __restrict__ bscan,
    int* __restrict__ offs, int* __restrict__ cursor)
{
  int i = blockIdx.x * 1024 + threadIdx.x;
  if (i >= NR) return;
  int o = offs[i + 1] + bscan[blockIdx.x];
  offs[i + 1] = o;
  cursor[i] = o - counts[i];
  if (i == 0) offs[0] = 0;
}

__global__ __launch_bounds__(256) void k_fill(
    const int* __restrict__ src, const int* __restrict__ dst,
    const int* __restrict__ et, int* __restrict__ cursor,
    int* __restrict__ elist)
{
  int e = blockIdx.x * 256 + threadIdx.x;
  if (e >= Ee) return;
  int pos = atomicAdd(&cursor[et[e] * Nn + dst[e]], 1);
  elist[pos] = src[e];
}

// ---------------- x -> bf16 shadow copy -------------------------------------
__global__ __launch_bounds__(256) void k_cvt(
    const float* __restrict__ x, unsigned short* __restrict__ hb)
{
  int i = blockIdx.x * 256 + threadIdx.x;
  if (i >= (Nn * Dd) / 4) return;
  const float4 v = *(const float4*)&x[(size_t)i * 4];
  ushort4 o;
  o.x = bf16_rne(v.x); o.y = bf16_rne(v.y);
  o.z = bf16_rne(v.z); o.w = bf16_rne(v.w);
  *(ushort4*)&hb[(size_t)i * 4] = o;
}

// ---------------- weight prep: W -> W^T split-bf16 (hi/lo) ------------------
__global__ __launch_bounds__(256) void k_prep(
    const float* __restrict__ selfW, const float* __restrict__ W1,
    const float* __restrict__ W2, unsigned short* __restrict__ wtHi,
    unsigned short* __restrict__ wtLo)
{
  int i = blockIdx.x * 256 + threadIdx.x;
  if (i >= Ll * 5 * 4096) return;
  int l = i / (5 * 4096);
  int rem = i - l * 5 * 4096;
  int m = rem >> 12;
  int e = rem & 4095;
  int k = e >> 6, c = e & 63;
  const float* p;
  if (m == 0)      p = selfW + (size_t)l * 4096;
  else if (m == 1) p = W1 + ((size_t)l * 2 + 0) * 4096;
  else if (m == 2) p = W2 + ((size_t)l * 2 + 0) * 4096;
  else if (m == 3) p = W1 + ((size_t)l * 2 + 1) * 4096;
  else             p = W2 + ((size_t)l * 2 + 1) * 4096;
  float w = p[e];
  unsigned short hi = bf16_rne(w);
  unsigned short lo = bf16_rne(w - bf16_tof(hi));
  size_t o = ((size_t)(l * 5 + m) * 64 + c) * 64 + k;
  wtHi[o] = hi;
  wtLo[o] = lo;
}

// ====== fused per-layer update: (task, relation) per wave + LDS combine =====
#define WOFF(m, c, ks) ((size_t)(m)*4096 + (size_t)(c)*64 + (ks)*32 + koff)

__global__ __launch_bounds__(128, 5) void k_update(
    const float* __restrict__ h, const unsigned short* __restrict__ hb,
    const int* __restrict__ offs, const int* __restrict__ elist,
    const unsigned short* __restrict__ wtHi, const unsigned short* __restrict__ wtLo,
    const float* __restrict__ selfb, const float* __restrict__ eps,
    const float* __restrict__ b1, const float* __restrict__ b2,
    float* __restrict__ hn, unsigned short* __restrict__ hnb, int l)
{
  __shared__ __align__(16) unsigned short tbh[2][16 * 72];
  __shared__ __align__(16) unsigned short tbl[2][16 * 72];
  __shared__ float xfer[16 * 65];       // padded: bank = row + col (mod 32)
  const int wave = threadIdx.x >> 6;    // = relation r
  const int lane = threadIdx.x & 63;
  const int task = blockIdx.x;
  const int r = wave;
  const int idx15 = lane & 15;
  const int kg = lane >> 4;
  const int koff = kg * 8;
  const int nodeA = task * 16 + idx15;

  // h row fragment (row = idx15, features koff..koff+7 per kstep), f32
  float f[2][8];
  {
    const float* hp = &h[(size_t)nodeA * 64 + koff];
    const float4 a0 = *(const float4*)(hp);
    const float4 a1 = *(const float4*)(hp + 4);
    const float4 b0 = *(const float4*)(hp + 32);
    const float4 b1v = *(const float4*)(hp + 36);
    f[0][0] = a0.x; f[0][1] = a0.y; f[0][2] = a0.z; f[0][3] = a0.w;
    f[0][4] = a1.x; f[0][5] = a1.y; f[0][6] = a1.z; f[0][7] = a1.w;
    f[1][0] = b0.x; f[1][1] = b0.y; f[1][2] = b0.z; f[1][3] = b0.w;
    f[1][4] = b1v.x; f[1][5] = b1v.y; f[1][6] = b1v.z; f[1][7] = b1v.w;
  }

  const unsigned short* whi = wtHi + (size_t)l * 5 * 4096;
  const unsigned short* wlo = wtLo + (size_t)l * 5 * 4096;
  const int m1 = 1 + 2 * r, m2 = 2 + 2 * r;
  const float er = 1.0f + eps[l * Rr + r];

  // ---- CSR gather for relation r, bf16 rows (128 B/edge), 4-deep pipelined -
  float za[2][8];
#pragma unroll
  for (int ks = 0; ks < 2; ++ks)
#pragma unroll
    for (int j = 0; j < 8; ++j) za[ks][j] = 0.0f;
  {
    int aidx = r * Nn + nodeA;
    int jb = offs[aidx], je = offs[aidx + 1];
    int j = jb;
    for (; j + 3 < je; j += 4) {
      int s0 = elist[j], s1 = elist[j + 1], s2 = elist[j + 2], s3 = elist[j + 3];
      const unsigned short* q0 = &hb[(size_t)s0 * 64 + koff];
      const unsigned short* q1 = &hb[(size_t)s1 * 64 + koff];
      const unsigned short* q2 = &hb[(size_t)s2 * 64 + koff];
      const unsigned short* q3 = &hb[(size_t)s3 * 64 + koff];
      const uint4 a0 = *(const uint4*)(q0);
      const uint4 a1 = *(const uint4*)(q1);
      const uint4 a2 = *(const uint4*)(q2);
      const uint4 a3 = *(const uint4*)(q3);
      const uint4 b0 = *(const uint4*)(q0 + 32);
      const uint4 b1q = *(const uint4*)(q1 + 32);
      const uint4 b2q = *(const uint4*)(q2 + 32);
      const uint4 b3 = *(const uint4*)(q3 + 32);
      acc8(za[0], a0); acc8(za[0], a1); acc8(za[0], a2); acc8(za[0], a3);
      acc8(za[1], b0); acc8(za[1], b1q); acc8(za[1], b2q); acc8(za[1], b3);
    }
    for (; j < je; ++j) {
      const unsigned short* q = &hb[(size_t)elist[j] * 64 + koff];
      const uint4 a = *(const uint4*)(q);
      const uint4 b = *(const uint4*)(q + 32);
      acc8(za[0], a); acc8(za[1], b);
    }
  }

  // z = er*h + za -> split bf16
  short8 zhi[2], zlo[2];
#pragma unroll
  for (int ks = 0; ks < 2; ++ks)
#pragma unroll
    for (int j = 0; j < 8; ++j) {
      float zf = er * f[ks][j] + za[ks][j];
      unsigned short hb2 = bf16_rne(zf);
      zhi[ks][j] = (short)hb2;
      zlo[ks][j] = (short)bf16_rne(zf - bf16_tof(hb2));
    }

  // MLP1: tacc = relu(z @ W1_r + b1_r)
  f32x4 tacc[4];
#pragma unroll
  for (int cb = 0; cb < 4; ++cb) {
    float bi = b1[((size_t)l * 2 + r) * 64 + cb * 16 + idx15];
    tacc[cb] = (f32x4){bi, bi, bi, bi};
  }
#pragma unroll
  for (int cb = 0; cb < 4; ++cb) {
    int c = cb * 16 + idx15;
#pragma unroll
    for (int ks = 0; ks < 2; ++ks) {
      const short8 bh = *(const short8*)&whi[WOFF(m1, c, ks)];
      const short8 bl = *(const short8*)&wlo[WOFF(m1, c, ks)];
      tacc[cb] = __builtin_amdgcn_mfma_f32_16x16x32_bf16(zhi[ks], bh, tacc[cb], 0, 0, 0);
      tacc[cb] = __builtin_amdgcn_mfma_f32_16x16x32_bf16(zhi[ks], bl, tacc[cb], 0, 0, 0);
      tacc[cb] = __builtin_amdgcn_mfma_f32_16x16x32_bf16(zlo[ks], bh, tacc[cb], 0, 0, 0);
    }
  }
  // relu -> split-bf16 -> LDS transpose bounce (per-wave buffer, no barrier)
#pragma unroll
  for (int cb = 0; cb < 4; ++cb)
#pragma unroll
    for (int q = 0; q < 4; ++q) {
      float tv = fmaxf(tacc[cb][q], 0.0f);
      unsigned short hb2 = bf16_rne(tv);
      tbh[wave][(kg * 4 + q) * 72 + cb * 16 + idx15] = hb2;
      tbl[wave][(kg * 4 + q) * 72 + cb * 16 + idx15] = bf16_rne(tv - bf16_tof(hb2));
    }
  asm volatile("s_waitcnt lgkmcnt(0)" ::: "memory");
  __builtin_amdgcn_sched_barrier(0);
  short8 thi[2], tlo[2];
#pragma unroll
  for (int ks = 0; ks < 2; ++ks) {
    thi[ks] = *(const short8*)&tbh[wave][idx15 * 72 + ks * 32 + koff];
    tlo[ks] = *(const short8*)&tbl[wave][idx15 * 72 + ks * 32 + koff];
  }

  // MLP2 (+ wave1: self GEMM); facc = partial output
  f32x4 facc[4];
#pragma unroll
  for (int cb = 0; cb < 4; ++cb) {
    int c = cb * 16 + idx15;
    float bi = b2[((size_t)l * 2 + r) * 64 + c];
    if (wave == 1) bi += selfb[l * 64 + c];
    facc[cb] = (f32x4){bi, bi, bi, bi};
  }
#pragma unroll
  for (int cb = 0; cb < 4; ++cb) {
    int c = cb * 16 + idx15;
#pragma unroll
    for (int ks = 0; ks < 2; ++ks) {
      const short8 bh = *(const short8*)&whi[WOFF(m2, c, ks)];
      const short8 bl = *(const short8*)&wlo[WOFF(m2, c, ks)];
      facc[cb] = __builtin_amdgcn_mfma_f32_16x16x32_bf16(thi[ks], bh, facc[cb], 0, 0, 0);
      facc[cb] = __builtin_amdgcn_mfma_f32_16x16x32_bf16(thi[ks], bl, facc[cb], 0, 0, 0);
      facc[cb] = __builtin_amdgcn_mfma_f32_16x16x32_bf16(tlo[ks], bh, facc[cb], 0, 0, 0);
    }
  }
  if (wave == 1) {
    short8 ahi[2], alo[2];
#pragma unroll
    for (int ks = 0; ks < 2; ++ks)
#pragma unroll
      for (int j = 0; j < 8; ++j) {
        unsigned short hb2 = bf16_rne(f[ks][j]);
        ahi[ks][j] = (short)hb2;
        alo[ks][j] = (short)bf16_rne(f[ks][j] - bf16_tof(hb2));
      }
#pragma unroll
    for (int cb = 0; cb < 4; ++cb) {
      int c = cb * 16 + idx15;
#pragma unroll
      for (int ks = 0; ks < 2; ++ks) {
        const short8 bh = *(const short8*)&whi[WOFF(0, c, ks)];
        const short8 bl = *(const short8*)&wlo[WOFF(0, c, ks)];
        facc[cb] = __builtin_amdgcn_mfma_f32_16x16x32_bf16(ahi[ks], bh, facc[cb], 0, 0, 0);
        facc[cb] = __builtin_amdgcn_mfma_f32_16x16x32_bf16(ahi[ks], bl, facc[cb], 0, 0, 0);
        facc[cb] = __builtin_amdgcn_mfma_f32_16x16x32_bf16(alo[ks], bh, facc[cb], 0, 0, 0);
      }
    }
    // deposit partial for wave0 to combine
#pragma unroll
    for (int cb = 0; cb < 4; ++cb)
#pragma unroll
      for (int q = 0; q < 4; ++q)
        xfer[(kg * 4 + q) * 65 + cb * 16 + idx15] = facc[cb][q];
  }
  __syncthreads();
  if (wave == 0) {
#pragma unroll
    for (int cb = 0; cb < 4; ++cb)
#pragma unroll
      for (int q = 0; q < 4; ++q) {
        int row = kg * 4 + q, col = cb * 16 + idx15;
        float v = facc[cb][q] + xfer[row * 65 + col];
        size_t o = ((size_t)task * 16 + row) * 64 + col;
        hn[o] = v;
        hnb[o] = bf16_rne(v);
      }
  }
}

// ---------------- global mean pool: segmented reduction (batch is sorted) ---
__global__ __launch_bounds__(256) void k_pool(
    const float* __restrict__ h, const int* __restrict__ batch,
    float* __restrict__ sums, float* __restrict__ cnts)
{
  int w = blockIdx.x * 4 + (threadIdx.x >> 6);
  int lane = threadIdx.x & 63;
  int start = w * 64;
  if (start >= Nn) return;
  int cnt = min(64, Nn - start);
  int bg = batch[min(start + lane, Nn - 1)];
  int cur = __shfl(bg, 0, 64);
  float acc = 0.0f;
  int run = 0;
  for (int i = 0; i < cnt; ++i) {
    int g = __shfl(bg, i, 64);
    float v = h[(size_t)(start + i) * 64 + lane];
    if (g != cur) {
      atomicAdd(&sums[(size_t)cur * 64 + lane], acc);
      if (lane == 0) atomicAdd(&cnts[cur], (float)run);
      acc = 0.0f; run = 0; cur = g;
    }
    acc += v; run++;
  }
  atomicAdd(&sums[(size_t)cur * 64 + lane], acc);
  if (lane == 0) atomicAdd(&cnts[cur], (float)run);
}

// ---------------- head: pooled -> relu(lin1) -> lin2 (wave per graph) -------
__global__ __launch_bounds__(256) void k_head(
    const float* __restrict__ sums, const float* __restrict__ cnts,
    const float* __restrict__ l1W, const float* __restrict__ l1b,
    const float* __restrict__ l2W, const float* __restrict__ l2b,
    float* __restrict__ out)
{
  int wave = threadIdx.x >> 6;
  int lane = threadIdx.x & 63;
  int g = blockIdx.x * 4 + wave;
  if (g >= Gg) return;
  float p = sums[(size_t)g * Dd + lane] / fmaxf(cnts[g], 1.0f);
  float t = l1b[lane];
#pragma unroll
  for (int k = 0; k < Dd; ++k)
    t += __shfl(p, k, 64) * l1W[k * Dd + lane];
  t = fmaxf(t, 0.0f);
  float o = (lane < Cc) ? l2b[lane] : 0.0f;
#pragma unroll
  for (int k = 0; k < Dd; ++k) {
    float w = (lane < Cc) ? l2W[k * Cc + lane] : 0.0f;
    o += __shfl(t, k, 64) * w;
  }
  if (lane < Cc) out[(size_t)g * Cc + lane] = o;
}

extern "C" void kernel_launch(void* const* d_in, const int* in_sizes, int n_in,
                              void* d_out, int out_size, void* d_ws, size_t ws_size,
                              hipStream_t stream)
{
  const float* x     = (const float*)d_in[0];
  const int*   ei    = (const int*)d_in[1];
  const int*   et    = (const int*)d_in[2];
  const int*   batch = (const int*)d_in[3];
  const float* selfW = (const float*)d_in[4];
  const float* selfb = (const float*)d_in[5];
  const float* eps   = (const float*)d_in[6];
  const float* W1    = (const float*)d_in[7];
  const float* b1    = (const float*)d_in[8];
  const float* W2    = (const float*)d_in[9];
  const float* b2    = (const float*)d_in[10];
  const float* l1W   = (const float*)d_in[11];
  const float* l1b   = (const float*)d_in[12];
  const float* l2W   = (const float*)d_in[13];
  const float* l2b   = (const float*)d_in[14];
  float* out = (float*)d_out;

  // ws layout:
  // buf0[N*D]f buf1[N*D]f hb0[N*D]u16 hb1[N*D]u16 sums[G*D]f cnts[G]f
  // wtHi/wtLo[15*4096]u16 counts[NR]i offs[NR+1]i cursor[NR]i btot/bscan[NB]i elist[E]i
  float* buf0 = (float*)d_ws;
  float* buf1 = buf0 + (size_t)Nn * Dd;
  unsigned short* hb0 = (unsigned short*)(buf1 + (size_t)Nn * Dd);
  unsigned short* hb1 = hb0 + (size_t)Nn * Dd;
  float* sums = (float*)(hb1 + (size_t)Nn * Dd);
  float* cnts = sums + (size_t)Gg * Dd;
  unsigned short* wtHi = (unsigned short*)(cnts + Gg);
  unsigned short* wtLo = wtHi + (size_t)Ll * 5 * 4096;
  int* counts = (int*)(wtLo + (size_t)Ll * 5 * 4096);
  int* offs   = counts + NR;
  int* cursor = offs + NR + 1;
  int* btot   = cursor + NR;
  int* bscan  = btot + NB;
  int* elist  = bscan + NB;

  const int* src = ei;
  const int* dst = ei + Ee;

  hipMemsetAsync(sums, 0, (size_t)(Gg * Dd + Gg) * sizeof(float), stream);
  hipMemsetAsync(counts, 0, (size_t)NR * sizeof(int), stream);
  k_prep<<<(Ll * 5 * 4096 + 255) / 256, 256, 0, stream>>>(selfW, W1, W2, wtHi, wtLo);
  k_cvt<<<(Nn * Dd / 4 + 255) / 256, 256, 0, stream>>>(x, hb0);

  // CSR build (graph static across layers)
  k_hist<<<(Ee + 255) / 256, 256, 0, stream>>>(dst, et, counts);
  k_scan1<<<NB, 1024, 0, stream>>>(counts, offs, btot);
  k_scan2<<<1, 128, 0, stream>>>(btot, bscan);
  k_scan3<<<NB, 1024, 0, stream>>>(counts, bscan, offs, cursor);
  k_fill<<<(Ee + 255) / 256, 256, 0, stream>>>(src, dst, et, cursor, elist);

  const float* h = x;
  const unsigned short* hbc = hb0;
  float* hn = buf0;
  unsigned short* hnb = hb1;
  for (int l = 0; l < Ll; ++l) {
    k_update<<<NT, 128, 0, stream>>>(h, hbc, offs, elist, wtHi, wtLo,
                                     selfb, eps, b1, b2, hn, hnb, l);
    h = hn;
    hbc = hnb;
    hn = (hn == buf0) ? buf1 : buf0;
    hnb = (hnb == hb0) ? hb1 : hb0;
  }
  k_pool<<<(Nn / 64 + 4) / 4, 256, 0, stream>>>(h, batch, sums, cnts);
  k_head<<<32, 256, 0, stream>>>(sums, cnts, l1W, l1b, l2W, l2b, out);
}